// Round 10
// baseline (284.802 us; speedup 1.0000x reference)
//
#include <hip/hip_runtime.h>
#include <hip/hip_bf16.h>
#include <stdint.h>

typedef unsigned short u16;
typedef __attribute__((ext_vector_type(8))) short short8;
typedef __attribute__((ext_vector_type(4))) float f32x4;

#define DEVI static __device__ __forceinline__

constexpr int B = 32, R = 10, N = 512, H = 128, Q = 256, NB = 16;
constexpr int KWB = 2560;  // (DN+DR)*R

DEVI u16 f2u(float f) { return __builtin_bit_cast(unsigned short, __float2bfloat16(f)); }
DEVI float u2f(u16 u) { union { uint32_t i; float f; } c; c.i = ((uint32_t)u) << 16; return c.f; }

DEVI float wredmax(float v) { for (int o = 32; o; o >>= 1) v = fmaxf(v, __shfl_xor(v, o)); return v; }
DEVI float wredsum(float v) { for (int o = 32; o; o >>= 1) v += __shfl_xor(v, o); return v; }

DEVI short8 cvt8(const float* p) {
  float4 f0 = *(const float4*)p;
  float4 f1 = *(const float4*)(p + 4);
  short8 v;
  v[0] = (short)f2u(f0.x); v[1] = (short)f2u(f0.y);
  v[2] = (short)f2u(f0.z); v[3] = (short)f2u(f0.w);
  v[4] = (short)f2u(f1.x); v[5] = (short)f2u(f1.y);
  v[6] = (short)f2u(f1.z); v[7] = (short)f2u(f1.w);
  return v;
}

// ---------------- merged prep: linWb | WbB | WwB(pad32) | vv | obs_prep | obsT ----------------
__global__ __launch_bounds__(256) void k_prep(
    const float* __restrict__ linW, u16* __restrict__ linWb,
    const float* __restrict__ Wb, u16* __restrict__ WbB,
    const float* __restrict__ Ww, u16* __restrict__ WwB,
    const float* __restrict__ rf, float* __restrict__ vv,
    const float* __restrict__ obs, const float* __restrict__ wC,
    const float* __restrict__ wQ, const float* __restrict__ wCQ,
    u16* __restrict__ obsW, float* __restrict__ a_o, float* __restrict__ d_o,
    u16* __restrict__ obsT) {
  int bid = blockIdx.x, t = threadIdx.x;
  __shared__ float sa[4], sd[4];
  __shared__ u16 tile[32][33];
  if (bid < 64) {                       // linW f32 -> bf16 (v4)
    int i = bid * 256 + t;
    float4 f = ((const float4*)linW)[i];
    ushort4 o;
    o.x = f2u(f.x); o.y = f2u(f.y); o.z = f2u(f.z); o.w = f2u(f.w);
    ((ushort4*)linWb)[i] = o;
  } else if (bid < 144) {               // WbB[r][k][d]
    int rk = (bid - 64) * 2 + (t >> 7);
    int d = t & 127;
    int r = rk / NB, k = rk % NB;
    WbB[(long)rk * 128 + d] = f2u(Wb[(long)k * KWB + r * 256 + d]);
  } else if (bid < 160) {               // WwB[h][kb] padded to 32
    int idx = (bid - 144) * 256 + t;
    int h = idx >> 5, kb = idx & 31;
    WwB[idx] = (kb < NB) ? f2u(Ww[h * NB + kb]) : (u16)0;
  } else if (bid < 1440) {              // vv
    int w = t >> 6, lane = t & 63;
    int gid = (bid - 160) * 4 + w;
    int b = gid / (R * NB), rk = gid % (R * NB), r = rk / NB, k = rk % NB;
    float s = 0.f;
    for (int dd = 0; dd < 2; ++dd) {
      int d = lane + dd * 64;
      s += rf[((long)b * R + r) * H + d] * Wb[(long)k * KWB + r * 256 + 128 + d];
    }
    s = wredsum(s);
    if (lane == 0) vv[((long)b * R + r) * NB + k] = s;
  } else if (bid < 5536) {              // obs prep: 2 rows per block
    int row = (bid - 1440) * 2 + (t >> 7);
    int tt = t & 127;
    float x = obs[(long)row * H + tt];
    obsW[(long)row * H + tt] = f2u(x * wCQ[tt]);
    float aa = wredsum(x * wC[tt]);
    float dd2 = wredsum(x * wQ[tt]);
    int wv = t >> 6;
    if ((t & 63) == 0) { sa[wv] = aa; sd[wv] = dd2; }
    __syncthreads();
    if ((t & 127) == 0) {
      int h = t >> 7;
      a_o[row] = sa[h * 2] + sa[h * 2 + 1];
      d_o[row] = sd[h * 2] + sd[h * 2 + 1];
    }
  } else {                              // obsT transpose tiles
    int id = bid - 5536;
    int cx = id & 3, ry = (id >> 2) & 7, b = id >> 5;
    int c0 = cx * 32, r0 = ry * 32;
    int tx = t & 31, ty = t >> 5;
    for (int i = 0; i < 4; i++) {
      int r = r0 + ty + i * 8, c = c0 + tx;
      tile[ty + i * 8][tx] = f2u(obs[((long)b * Q + r) * H + c]);
    }
    __syncthreads();
    for (int i = 0; i < 4; i++) {
      int c = c0 + ty + i * 8, r = r0 + tx;
      obsT[((long)b * H + c) * Q + r] = tile[tx][ty + i * 8];
    }
  }
}

// ---------------- k_tt: tT[b,r](16 x N) = WbB[r] @ nf[b]^T + vv[b,r]  (XCD-swizzled)
__global__ __launch_bounds__(512) void k_tt(const u16* __restrict__ WbB, const float* __restrict__ nf,
                                            const float* __restrict__ vv, u16* __restrict__ tT) {
  int f = blockIdx.x + 4 * blockIdx.y;         // 128 blocks
  int g = (f & 7) * 16 + (f >> 3);
  int bx = g & 3, b = g >> 2;
  int t = threadIdx.x;
  __shared__ __align__(16) u16 tile[128][128];
  {
    int row = t >> 2, q = (t & 3) * 32;
    const float* src = nf + ((long)b * N + bx * 128 + row) * H + q;
    int sw = (row & 7) << 3;
    for (int j = 0; j < 4; j++) {
      short8 v = cvt8(src + j * 8);
      *(short8*)&tile[row][(q + j * 8) ^ sw] = v;
    }
  }
  __syncthreads();
  int w = t >> 6, lane = t & 63;
  int rw = lane & 15, kq = lane >> 4;
  for (int r = w; r < R; r += 8) {
    f32x4 acc[8] = {};
    for (int kit = 0; kit < H; kit += 32) {
      short8 av = *(const short8*)(WbB + ((long)r * NB + rw) * 128 + kit + kq * 8);
#pragma unroll
      for (int nt = 0; nt < 8; nt++) {
        int brow = nt * 16 + rw;
        short8 bv = *(const short8*)&tile[brow][(kit + kq * 8) ^ ((brow & 7) << 3)];
        acc[nt] = __builtin_amdgcn_mfma_f32_16x16x32_bf16(av, bv, acc[nt], 0, 0, 0);
      }
    }
    long rbase = (long)(b * R + r) * NB;
#pragma unroll
    for (int nt = 0; nt < 8; nt++) {
      int gc = bx * 128 + nt * 16 + rw;
      for (int i = 0; i < 4; i++) {
        int gr = kq * 4 + i;
        tT[(rbase + gr) * N + gc] = f2u(acc[nt][i] + vv[rbase + gr]);
      }
    }
  }
}

// ---------------- RGCN mega-kernel (8 waves, XCD-swizzled)
__global__ __launch_bounds__(512) void k_rgcn(
    const float* __restrict__ adj, const u16* __restrict__ tT,
    const u16* __restrict__ WwB, const float* __restrict__ rb,
    const float* __restrict__ wC, const float* __restrict__ wQ,
    u16* __restrict__ nr, u16* __restrict__ nrT,
    float* __restrict__ b_n, float* __restrict__ c_n) {
  int f = blockIdx.x + 32 * blockIdx.y;        // 1024 blocks
  int g = (f & 7) * 128 + (f >> 3);
  int ntile = g & 31, b = g >> 5;
  int n0 = ntile * 16;
  int tid = threadIdx.x;
  int w = tid >> 6, lane = tid & 63;
  int rw = lane & 15, kq = lane >> 4;
  __shared__ float hred[8][16][17];
  __shared__ __align__(16) u16 hbf[16][32];
  __shared__ float bpc[8][16][2];
  float rbv = rb[0];

  f32x4 acc = {0.f, 0.f, 0.f, 0.f};
#pragma unroll 4
  for (int j = 0; j < 20; ++j) {
    int kkk = w + 8 * j;
    int r = kkk >> 4, k = (kkk & 15) * 32;
    short8 av = cvt8(adj + (((long)(b * R + r) * N) + n0 + rw) * N + k + kq * 8);
    short8 bv = *(const short8*)(tT + ((long)(b * R + r) * NB + rw) * N + k + kq * 8);
    acc = __builtin_amdgcn_mfma_f32_16x16x32_bf16(av, bv, acc, 0, 0, 0);
  }
  for (int i = 0; i < 4; i++) hred[w][kq * 4 + i][rw] = acc[i];
  __syncthreads();
  if (tid < 256) {
    int n = tid >> 4, kb = tid & 15;
    float s = 0.f;
    for (int ww = 0; ww < 8; ww++) s += hred[ww][n][kb];
    hbf[n][kb] = f2u(s);
    hbf[n][kb + 16] = 0;
  }
  __syncthreads();

  short8 av = *(const short8*)&hbf[rw][kq * 8];
  short8 bv = *(const short8*)(WwB + (long)(w * 16 + rw) * 32 + kq * 8);
  f32x4 a2 = {0.f, 0.f, 0.f, 0.f};
  a2 = __builtin_amdgcn_mfma_f32_16x16x32_bf16(av, bv, a2, 0, 0, 0);
  int h = w * 16 + rw;
  float wq = wQ[h], wc = wC[h];
  float bsum[4], csum[4];
  for (int i = 0; i < 4; i++) {
    float s = 1.f / (1.f + expf(-(a2[i] + rbv)));
    int n = n0 + kq * 4 + i;
    u16 sv = f2u(s);
    nr[((long)b * N + n) * H + h] = sv;
    nrT[((long)b * H + h) * N + n] = sv;
    bsum[i] = s * wq;
    csum[i] = s * wc;
  }
  for (int i = 0; i < 4; i++) {
    for (int o = 8; o; o >>= 1) { bsum[i] += __shfl_xor(bsum[i], o); csum[i] += __shfl_xor(csum[i], o); }
  }
  if (rw == 0)
    for (int i = 0; i < 4; i++) { bpc[w][kq * 4 + i][0] = bsum[i]; bpc[w][kq * 4 + i][1] = csum[i]; }
  __syncthreads();
  if (tid < 32) {
    int ns = tid & 15, which = tid >> 4;
    float s = 0.f;
    for (int ww = 0; ww < 8; ww++) s += bpc[ww][ns][which];
    (which ? c_n : b_n)[(long)b * N + n0 + ns] = s;
  }
}

// ---------------- k_mm_soft (XCD-swizzled): S-tile in regs; row softmaxes; sq1, sc2, ST.
__global__ __launch_bounds__(512) void k_mm_soft(
    const u16* __restrict__ obsW, const u16* __restrict__ nr,
    const float* __restrict__ b_n, const float* __restrict__ c_n,
    const float* __restrict__ nmask,
    u16* __restrict__ sq1, u16* __restrict__ sc2, u16* __restrict__ ST) {
  int f = blockIdx.x + 16 * blockIdx.y;        // 512 blocks
  int g = (f & 7) * 64 + (f >> 3);
  int mt = g & 15, b = g >> 4;
  int tid = threadIdx.x;
  int w = tid >> 6, lane = tid & 63;
  int rw = lane & 15, kq = lane >> 4;
  __shared__ float sm1[8][16], sm2[8][16], ss1[8][16], ss2[8][16];

  const u16* ap = obsW + ((long)b * Q + mt * 16 + rw) * H + kq * 8;
  const u16* bp = nr + ((long)b * N + w * 64 + rw) * H + kq * 8;
  f32x4 acc[4] = {};
  for (int k = 0; k < H; k += 32) {
    short8 av = *(const short8*)(ap + k);
#pragma unroll
    for (int nt = 0; nt < 4; nt++) {
      short8 bv = *(const short8*)(bp + (long)nt * 16 * H + k);
      acc[nt] = __builtin_amdgcn_mfma_f32_16x16x32_bf16(av, bv, acc[nt], 0, 0, 0);
    }
  }
  float bn[4], cn[4];
  bool mk[4];
  int gcv[4];
#pragma unroll
  for (int nt = 0; nt < 4; nt++) {
    int gc = w * 64 + nt * 16 + rw;
    gcv[nt] = gc;
    mk[nt] = nmask[(long)b * N + gc] > 0.f;
    bn[nt] = b_n[(long)b * N + gc];
    cn[nt] = c_n[(long)b * N + gc];
  }
#pragma unroll
  for (int nt = 0; nt < 4; nt++) {
    long stb = ((long)b * N + gcv[nt]) * Q + mt * 16 + kq * 4;
    for (int i = 0; i < 4; i++) ST[stb + i] = f2u(acc[nt][i]);
  }
  float m1[4], m2[4];
  for (int i = 0; i < 4; i++) { m1[i] = -1e30f; m2[i] = -1e30f; }
#pragma unroll
  for (int nt = 0; nt < 4; nt++)
    for (int i = 0; i < 4; i++) {
      float s = acc[nt][i];
      if (mk[nt]) { m1[i] = fmaxf(m1[i], s + bn[nt]); m2[i] = fmaxf(m2[i], s + cn[nt]); }
    }
  for (int i = 0; i < 4; i++)
    for (int o = 8; o; o >>= 1) { m1[i] = fmaxf(m1[i], __shfl_xor(m1[i], o)); m2[i] = fmaxf(m2[i], __shfl_xor(m2[i], o)); }
  if (rw == 0)
    for (int i = 0; i < 4; i++) { sm1[w][kq * 4 + i] = m1[i]; sm2[w][kq * 4 + i] = m2[i]; }
  __syncthreads();
  for (int i = 0; i < 4; i++) {
    float g1 = -1e30f, g2 = -1e30f;
    for (int ww = 0; ww < 8; ww++) { g1 = fmaxf(g1, sm1[ww][kq * 4 + i]); g2 = fmaxf(g2, sm2[ww][kq * 4 + i]); }
    m1[i] = g1; m2[i] = g2;
  }
  float e1[4][4], e2[4][4];
  float s1[4] = {0.f, 0.f, 0.f, 0.f}, s2[4] = {0.f, 0.f, 0.f, 0.f};
#pragma unroll
  for (int nt = 0; nt < 4; nt++)
    for (int i = 0; i < 4; i++) {
      float s = acc[nt][i];
      float a = mk[nt] ? expf(s + bn[nt] - m1[i]) : 0.f;
      float c = mk[nt] ? expf(s + cn[nt] - m2[i]) : 0.f;
      e1[nt][i] = a; e2[nt][i] = c;
      s1[i] += a; s2[i] += c;
    }
  for (int i = 0; i < 4; i++)
    for (int o = 8; o; o >>= 1) { s1[i] += __shfl_xor(s1[i], o); s2[i] += __shfl_xor(s2[i], o); }
  if (rw == 0)
    for (int i = 0; i < 4; i++) { ss1[w][kq * 4 + i] = s1[i]; ss2[w][kq * 4 + i] = s2[i]; }
  __syncthreads();
  float r1[4], r2[4];
  for (int i = 0; i < 4; i++) {
    float g1 = 0.f, g2 = 0.f;
    for (int ww = 0; ww < 8; ww++) { g1 += ss1[ww][kq * 4 + i]; g2 += ss2[ww][kq * 4 + i]; }
    r1[i] = 1.f / g1; r2[i] = 1.f / g2;
  }
#pragma unroll
  for (int nt = 0; nt < 4; nt++)
    for (int i = 0; i < 4; i++) {
      long ob = ((long)b * Q + mt * 16 + kq * 4 + i) * N + gcv[nt];
      sq1[ob] = f2u(e1[nt][i] * r1[i]);
      sc2[ob] = f2u(e2[nt][i] * r2[i]);
    }
}

// ---------------- col softmax: wave per (b,n) row, 4 waves/block
__global__ __launch_bounds__(256) void k_soft_col(
    const u16* __restrict__ ST, const float* __restrict__ a_o, const float* __restrict__ d_o,
    const float* __restrict__ omask, u16* __restrict__ sc1T, u16* __restrict__ sq2) {
  int w = threadIdx.x >> 6, lane = threadIdx.x & 63;
  long rn = (long)blockIdx.x * 4 + w;   // 16384 rows total
  int b = (int)(rn >> 9);
  float v1[4], v2[4];
  const u16* st = ST + rn * Q + lane * 4;
  for (int i = 0; i < 4; i++) {
    int o = lane * 4 + i;
    float mv = u2f(st[i]);
    bool on = omask[(long)b * Q + o] > 0.f;
    v1[i] = on ? a_o[(long)b * Q + o] + mv : -1e30f;
    v2[i] = on ? d_o[(long)b * Q + o] + mv : -1e30f;
  }
  float m1 = wredmax(fmaxf(fmaxf(v1[0], v1[1]), fmaxf(v1[2], v1[3])));
  float m2 = wredmax(fmaxf(fmaxf(v2[0], v2[1]), fmaxf(v2[2], v2[3])));
  float e1[4], e2[4], s1 = 0.f, s2 = 0.f;
  for (int i = 0; i < 4; i++) {
    e1[i] = expf(v1[i] - m1); e2[i] = expf(v2[i] - m2);
    s1 += e1[i]; s2 += e2[i];
  }
  s1 = wredsum(s1); s2 = wredsum(s2);
  float r1 = 1.f / s1, r2 = 1.f / s2;
  for (int i = 0; i < 4; i++) {
    sc1T[rn * Q + lane * 4 + i] = f2u(e1[i] * r1);
    sq2[rn * Q + lane * 4 + i] = f2u(e2[i] * r2);
  }
}

// ---------------- 16x128 GEMM tile worker ----------------
DEVI void gemm_tile(const u16* A, const u16* Bt, u16* C, int Mdim, int Kdim,
                    long sA, long sBt, long sC, int tc, int batch, int mt, int lane) {
  if (mt * 16 >= Mdim) return;
  int rw = lane & 15, kq = lane >> 4;
  const u16* ap = A + (long)batch * sA + (long)(mt * 16 + rw) * Kdim + kq * 8;
  const u16* bp = Bt + (long)batch * sBt + (long)rw * Kdim + kq * 8;
  f32x4 acc[8] = {};
  for (int k = 0; k < Kdim; k += 32) {
    short8 av = *(const short8*)(ap + k);
#pragma unroll
    for (int nt = 0; nt < 8; nt++) {
      short8 bv = *(const short8*)(bp + (long)nt * 16 * Kdim + k);
      acc[nt] = __builtin_amdgcn_mfma_f32_16x16x32_bf16(av, bv, acc[nt], 0, 0, 0);
    }
  }
#pragma unroll
  for (int nt = 0; nt < 8; nt++) {
    int gc = nt * 16 + rw;
    for (int i = 0; i < 4; i++) {
      int gr = mt * 16 + kq * 4 + i;
      long idx = tc ? ((long)gc * Mdim + gr) : ((long)gr * H + gc);
      C[(long)batch * sC + idx] = f2u(acc[nt][i]);
    }
  }
}

// ---------------- phase A: P1 | T2T | T1T | P2 (4096 tiles, XCD-swizzled 1D)
__global__ __launch_bounds__(64) void k_gemmA(
    const u16* __restrict__ sq1, const u16* __restrict__ sc2,
    const u16* __restrict__ sc1T, const u16* __restrict__ sq2,
    const u16* __restrict__ nrT, const u16* __restrict__ obsT,
    u16* __restrict__ P1, u16* __restrict__ T2T, u16* __restrict__ T1T, u16* __restrict__ P2) {
  int bid = blockIdx.x;
  int t = (bid & 7) * 512 + (bid >> 3);
  int z = t >> 10, rem = t & 1023, batch = rem >> 5, mt = rem & 31;
  int lane = threadIdx.x;
  if (z == 0)      gemm_tile(sq1,  nrT,  P1,  Q, N, (long)Q * N, (long)H * N, (long)Q * H, 0, batch, mt, lane);
  else if (z == 1) gemm_tile(sc2,  nrT,  T2T, Q, N, (long)Q * N, (long)H * N, (long)H * Q, 1, batch, mt, lane);
  else if (z == 2) gemm_tile(sc1T, obsT, T1T, N, Q, (long)N * Q, (long)H * Q, (long)H * N, 1, batch, mt, lane);
  else             gemm_tile(sq2,  obsT, P2,  N, Q, (long)N * Q, (long)H * Q, (long)N * H, 0, batch, mt, lane);
}

// ---------------- phase B: Qm1 | Qm2 (2048 tiles, XCD-swizzled 1D)
__global__ __launch_bounds__(64) void k_gemmB(
    const u16* __restrict__ sq1, const u16* __restrict__ sq2,
    const u16* __restrict__ T1T, const u16* __restrict__ T2T,
    u16* __restrict__ Qm1, u16* __restrict__ Qm2) {
  int bid = blockIdx.x;
  int t = (bid & 7) * 256 + (bid >> 3);
  int z = t >> 10, rem = t & 1023, batch = rem >> 5, mt = rem & 31;
  int lane = threadIdx.x;
  if (z == 0) gemm_tile(sq1, T1T, Qm1, Q, N, (long)Q * N, (long)H * N, (long)Q * H, 0, batch, mt, lane);
  else        gemm_tile(sq2, T2T, Qm2, N, Q, (long)N * Q, (long)H * Q, (long)N * H, 0, batch, mt, lane);
}

// ---------------- phase C: concat + output linear (2048 tiles, XCD-swizzled 1D)
__global__ __launch_bounds__(64) void k_cat(
    const float* __restrict__ obs, const u16* __restrict__ nrr,
    const u16* __restrict__ P1, const u16* __restrict__ Qm1,
    const u16* __restrict__ P2, const u16* __restrict__ Qm2,
    const u16* __restrict__ Wt, const float* __restrict__ bias,
    float* __restrict__ out0, float* __restrict__ out1) {
  int bid = blockIdx.x;
  int t = (bid & 7) * 256 + (bid >> 3);
  int z = t >> 10, rem = t & 1023, batch = rem >> 5, mt = rem & 31;
  int Mdim = z ? N : Q;
  if (mt * 16 >= Mdim) return;
  const u16* P = z ? P2 : P1;
  const u16* Qm = z ? Qm2 : Qm1;
  float* out = z ? out1 : out0;
  int lane = threadIdx.x;
  int rw = lane & 15, kq = lane >> 4;
  long arow = (long)batch * Mdim + mt * 16 + rw;
  const u16* bp = Wt + (long)rw * (4 * H) + kq * 8;
  f32x4 acc[8] = {};
  for (int k = 0; k < 4 * H; k += 32) {
    int sec = k >> 7;
    int off = (k & 127) + kq * 8;
    long rb2 = arow * H + off;
    short8 av;
    if (sec == 0) {
      if (!z) av = cvt8(obs + rb2);
      else    av = *(const short8*)(nrr + rb2);
    } else if (sec == 1) {
      av = *(const short8*)(P + rb2);
    } else {
      float xf[8];
      if (!z) {
        const float* xp = obs + rb2;
        float4 f0 = *(const float4*)xp;
        float4 f1 = *(const float4*)(xp + 4);
        xf[0] = f0.x; xf[1] = f0.y; xf[2] = f0.z; xf[3] = f0.w;
        xf[4] = f1.x; xf[5] = f1.y; xf[6] = f1.z; xf[7] = f1.w;
      } else {
        short8 xv = *(const short8*)(nrr + rb2);
        for (int i = 0; i < 8; i++) xf[i] = u2f((u16)xv[i]);
      }
      short8 pv = *(const short8*)((sec == 2 ? P : Qm) + rb2);
      for (int i = 0; i < 8; i++) av[i] = (short)f2u(xf[i] * u2f((u16)pv[i]));
    }
#pragma unroll
    for (int nt = 0; nt < 8; nt++) {
      short8 bv = *(const short8*)(bp + (long)nt * 16 * (4 * H) + k);
      acc[nt] = __builtin_amdgcn_mfma_f32_16x16x32_bf16(av, bv, acc[nt], 0, 0, 0);
    }
  }
#pragma unroll
  for (int nt = 0; nt < 8; nt++) {
    int gc = nt * 16 + rw;
    float cb = bias[gc];
    for (int i = 0; i < 4; i++) {
      int gr = mt * 16 + kq * 4 + i;
      out[((long)batch * Mdim + gr) * H + gc] = acc[nt][i] + cb;
    }
  }
}

// ---------------- launch ----------------
extern "C" void kernel_launch(void* const* d_in, const int* in_sizes, int n_in,
                              void* d_out, int out_size, void* d_ws, size_t ws_size,
                              hipStream_t stream) {
  const float* nf    = (const float*)d_in[0];
  const float* rf    = (const float*)d_in[1];
  const float* adj   = (const float*)d_in[2];
  const float* obs   = (const float*)d_in[3];
  const float* nmask = (const float*)d_in[4];
  const float* omask = (const float*)d_in[5];
  const float* Wb    = (const float*)d_in[6];
  const float* Ww    = (const float*)d_in[7];
  const float* rb    = (const float*)d_in[8];
  const float* wC    = (const float*)d_in[9];
  const float* wQ    = (const float*)d_in[10];
  const float* wCQ   = (const float*)d_in[11];
  // d_in[12] = cq_bias: uniform shift along both softmax axes -> cancels, unused
  const float* linW  = (const float*)d_in[13];
  const float* linb  = (const float*)d_in[14];
  float* outp = (float*)d_out;

  char* w = (char*)d_ws;
  auto alloc = [&](size_t bytes) { char* p = w; w += (bytes + 255) & ~(size_t)255; return p; };
  u16*   linWb = (u16*)  alloc((size_t)H * 4 * H * 2);
  u16*   WbB   = (u16*)  alloc((size_t)R * NB * 128 * 2);
  u16*   WwB   = (u16*)  alloc((size_t)H * 32 * 2);
  float* vv    = (float*)alloc((size_t)B * R * NB * 4);
  u16*   obsW  = (u16*)  alloc((size_t)B * Q * H * 2);
  u16*   obsT  = (u16*)  alloc((size_t)B * H * Q * 2);
  float* a_o   = (float*)alloc((size_t)B * Q * 4);
  float* d_o   = (float*)alloc((size_t)B * Q * 4);
  float* b_n   = (float*)alloc((size_t)B * N * 4);
  float* c_n   = (float*)alloc((size_t)B * N * 4);
  u16*   nr    = (u16*)  alloc((size_t)B * N * H * 2);
  u16*   nrT   = (u16*)  alloc((size_t)B * H * N * 2);
  u16*   tT    = (u16*)  alloc((size_t)B * R * NB * N * 2);
  u16*   ST    = (u16*)  alloc((size_t)B * N * Q * 2);
  u16*   sq1   = (u16*)  alloc((size_t)B * Q * N * 2);
  u16*   sc2   = (u16*)  alloc((size_t)B * Q * N * 2);
  u16*   sc1T  = (u16*)  alloc((size_t)B * N * Q * 2);
  u16*   sq2   = (u16*)  alloc((size_t)B * N * Q * 2);
  u16*   P1    = (u16*)  alloc((size_t)B * Q * H * 2);
  u16*   T1T   = (u16*)  alloc((size_t)B * H * N * 2);
  u16*   Qm1   = (u16*)  alloc((size_t)B * Q * H * 2);
  u16*   P2    = (u16*)  alloc((size_t)B * N * H * 2);
  u16*   T2T   = (u16*)  alloc((size_t)B * H * Q * 2);
  u16*   Qm2   = (u16*)  alloc((size_t)B * N * H * 2);
  float* out1  = outp + (long)B * Q * H;

  // 1. prep
  k_prep<<<6560, 256, 0, stream>>>(linW, linWb, Wb, WbB, Ww, WwB,
                                   rf, vv, obs, wC, wQ, wCQ, obsW, a_o, d_o, obsT);
  // 2. tT
  k_tt<<<dim3(N / 128, B), 512, 0, stream>>>(WbB, nf, vv, tT);
  // 3. mega RGCN
  k_rgcn<<<dim3(N / 16, B), 512, 0, stream>>>(adj, tT, WwB, rb, wC, wQ, nr, nrT, b_n, c_n);
  // 4. S + row softmaxes
  k_mm_soft<<<dim3(Q / 16, B), 512, 0, stream>>>(obsW, nr, b_n, c_n, nmask, sq1, sc2, ST);
  // 5. col softmax (wave per row)
  k_soft_col<<<B * N / 4, 256, 0, stream>>>(ST, a_o, d_o, omask, sc1T, sq2);
  // 6. phase A GEMMs
  k_gemmA<<<4096, 64, 0, stream>>>(sq1, sc2, sc1T, sq2, nrT, obsT, P1, T2T, T1T, P2);
  // 7. phase B GEMMs
  k_gemmB<<<2048, 64, 0, stream>>>(sq1, sq2, T1T, T2T, Qm1, Qm2);
  // 8. concat + output linear
  k_cat<<<2048, 64, 0, stream>>>(obs, nr, P1, Qm1, P2, Qm2, linWb, linb, outp, out1);

  (void)in_sizes; (void)n_in; (void)out_size; (void)ws_size;
}

// Round 11
// 276.446 us; speedup vs baseline: 1.0302x; 1.0302x over previous
//
#include <hip/hip_runtime.h>
#include <hip/hip_bf16.h>
#include <stdint.h>

typedef unsigned short u16;
typedef __attribute__((ext_vector_type(8))) short short8;
typedef __attribute__((ext_vector_type(4))) float f32x4;

#define DEVI static __device__ __forceinline__

constexpr int B = 32, R = 10, N = 512, H = 128, Q = 256, NB = 16;
constexpr int KWB = 2560;  // (DN+DR)*R

DEVI u16 f2u(float f) { return __builtin_bit_cast(unsigned short, __float2bfloat16(f)); }
DEVI float u2f(u16 u) { union { uint32_t i; float f; } c; c.i = ((uint32_t)u) << 16; return c.f; }

DEVI float wredmax(float v) { for (int o = 32; o; o >>= 1) v = fmaxf(v, __shfl_xor(v, o)); return v; }
DEVI float wredsum(float v) { for (int o = 32; o; o >>= 1) v += __shfl_xor(v, o); return v; }

DEVI short8 cvt8(const float* p) {
  float4 f0 = *(const float4*)p;
  float4 f1 = *(const float4*)(p + 4);
  short8 v;
  v[0] = (short)f2u(f0.x); v[1] = (short)f2u(f0.y);
  v[2] = (short)f2u(f0.z); v[3] = (short)f2u(f0.w);
  v[4] = (short)f2u(f1.x); v[5] = (short)f2u(f1.y);
  v[6] = (short)f2u(f1.z); v[7] = (short)f2u(f1.w);
  return v;
}

DEVI void gload16(const float* gp, void* lp) {
  __builtin_amdgcn_global_load_lds(
      (__attribute__((address_space(1))) void*)(uintptr_t)gp,
      (__attribute__((address_space(3))) void*)lp, 16, 0, 0);
}

// ---------------- merged prep: linWb | WbB | WwB(pad32) | vv | obs_prep | obsT ----------------
__global__ __launch_bounds__(256) void k_prep(
    const float* __restrict__ linW, u16* __restrict__ linWb,
    const float* __restrict__ Wb, u16* __restrict__ WbB,
    const float* __restrict__ Ww, u16* __restrict__ WwB,
    const float* __restrict__ rf, float* __restrict__ vv,
    const float* __restrict__ obs, const float* __restrict__ wC,
    const float* __restrict__ wQ, const float* __restrict__ wCQ,
    u16* __restrict__ obsW, float* __restrict__ a_o, float* __restrict__ d_o,
    u16* __restrict__ obsT) {
  int bid = blockIdx.x, t = threadIdx.x;
  __shared__ float sa[4], sd[4];
  __shared__ u16 tile[32][33];
  if (bid < 64) {                       // linW f32 -> bf16 (v4)
    int i = bid * 256 + t;
    float4 f = ((const float4*)linW)[i];
    ushort4 o;
    o.x = f2u(f.x); o.y = f2u(f.y); o.z = f2u(f.z); o.w = f2u(f.w);
    ((ushort4*)linWb)[i] = o;
  } else if (bid < 144) {               // WbB[r][k][d]
    int rk = (bid - 64) * 2 + (t >> 7);
    int d = t & 127;
    int r = rk / NB, k = rk % NB;
    WbB[(long)rk * 128 + d] = f2u(Wb[(long)k * KWB + r * 256 + d]);
  } else if (bid < 160) {               // WwB[h][kb] padded to 32
    int idx = (bid - 144) * 256 + t;
    int h = idx >> 5, kb = idx & 31;
    WwB[idx] = (kb < NB) ? f2u(Ww[h * NB + kb]) : (u16)0;
  } else if (bid < 1440) {              // vv
    int w = t >> 6, lane = t & 63;
    int gid = (bid - 160) * 4 + w;
    int b = gid / (R * NB), rk = gid % (R * NB), r = rk / NB, k = rk % NB;
    float s = 0.f;
    for (int dd = 0; dd < 2; ++dd) {
      int d = lane + dd * 64;
      s += rf[((long)b * R + r) * H + d] * Wb[(long)k * KWB + r * 256 + 128 + d];
    }
    s = wredsum(s);
    if (lane == 0) vv[((long)b * R + r) * NB + k] = s;
  } else if (bid < 5536) {              // obs prep: 2 rows per block
    int row = (bid - 1440) * 2 + (t >> 7);
    int tt = t & 127;
    float x = obs[(long)row * H + tt];
    obsW[(long)row * H + tt] = f2u(x * wCQ[tt]);
    float aa = wredsum(x * wC[tt]);
    float dd2 = wredsum(x * wQ[tt]);
    int wv = t >> 6;
    if ((t & 63) == 0) { sa[wv] = aa; sd[wv] = dd2; }
    __syncthreads();
    if ((t & 127) == 0) {
      int h = t >> 7;
      a_o[row] = sa[h * 2] + sa[h * 2 + 1];
      d_o[row] = sd[h * 2] + sd[h * 2 + 1];
    }
  } else {                              // obsT transpose tiles
    int id = bid - 5536;
    int cx = id & 3, ry = (id >> 2) & 7, b = id >> 5;
    int c0 = cx * 32, r0 = ry * 32;
    int tx = t & 31, ty = t >> 5;
    for (int i = 0; i < 4; i++) {
      int r = r0 + ty + i * 8, c = c0 + tx;
      tile[ty + i * 8][tx] = f2u(obs[((long)b * Q + r) * H + c]);
    }
    __syncthreads();
    for (int i = 0; i < 4; i++) {
      int c = c0 + ty + i * 8, r = r0 + tx;
      obsT[((long)b * H + c) * Q + r] = tile[tx][ty + i * 8];
    }
  }
}

// ---------------- k_tt: tT[b,r](16 x N) = WbB[r] @ nf[b]^T + vv[b,r]  (XCD-swizzled)
__global__ __launch_bounds__(512) void k_tt(const u16* __restrict__ WbB, const float* __restrict__ nf,
                                            const float* __restrict__ vv, u16* __restrict__ tT) {
  int f = blockIdx.x + 4 * blockIdx.y;         // 128 blocks
  int g = (f & 7) * 16 + (f >> 3);
  int bx = g & 3, b = g >> 2;
  int t = threadIdx.x;
  __shared__ __align__(16) u16 tile[128][128];
  {
    int row = t >> 2, q = (t & 3) * 32;
    const float* src = nf + ((long)b * N + bx * 128 + row) * H + q;
    int sw = (row & 7) << 3;
    for (int j = 0; j < 4; j++) {
      short8 v = cvt8(src + j * 8);
      *(short8*)&tile[row][(q + j * 8) ^ sw] = v;
    }
  }
  __syncthreads();
  int w = t >> 6, lane = t & 63;
  int rw = lane & 15, kq = lane >> 4;
  for (int r = w; r < R; r += 8) {
    f32x4 acc[8] = {};
    for (int kit = 0; kit < H; kit += 32) {
      short8 av = *(const short8*)(WbB + ((long)r * NB + rw) * 128 + kit + kq * 8);
#pragma unroll
      for (int nt = 0; nt < 8; nt++) {
        int brow = nt * 16 + rw;
        short8 bv = *(const short8*)&tile[brow][(kit + kq * 8) ^ ((brow & 7) << 3)];
        acc[nt] = __builtin_amdgcn_mfma_f32_16x16x32_bf16(av, bv, acc[nt], 0, 0, 0);
      }
    }
    long rbase = (long)(b * R + r) * NB;
#pragma unroll
    for (int nt = 0; nt < 8; nt++) {
      int gc = bx * 128 + nt * 16 + rw;
      for (int i = 0; i < 4; i++) {
        int gr = kq * 4 + i;
        tT[(rbase + gr) * N + gc] = f2u(acc[nt][i] + vv[rbase + gr]);
      }
    }
  }
}

// ---------------- RGCN mega-kernel v2: double-buffered global_load_lds adj pipeline.
// grid (N/16, B), 512 threads (8 waves). Wave w owns K-cols [w*64,(w+1)*64) of each r.
__global__ __launch_bounds__(512) void k_rgcn(
    const float* __restrict__ adj, const u16* __restrict__ tT,
    const u16* __restrict__ WwB, const float* __restrict__ rb,
    const float* __restrict__ wC, const float* __restrict__ wQ,
    u16* __restrict__ nr, u16* __restrict__ nrT,
    float* __restrict__ b_n, float* __restrict__ c_n) {
  int f = blockIdx.x + 32 * blockIdx.y;        // 1024 blocks
  int g = (f & 7) * 128 + (f >> 3);
  int ntile = g & 31, b = g >> 5;
  int n0 = ntile * 16;
  int tid = threadIdx.x;
  int w = tid >> 6, lane = tid & 63;
  int rw = lane & 15, kq = lane >> 4;
  __shared__ __align__(16) float abuf[2][16][512];   // 64 KB, granule-XOR-swizzled
  __shared__ float hred[8][16][17];
  __shared__ __align__(16) u16 hbf[16][32];
  __shared__ float bpc[8][16][2];
  float rbv = rb[0];

  // stage adj[b,r][n0..n0+16][0..512] f32 into abuf[pb]; LDS dest linear, source
  // granule-XOR-preswizzled (gg = sg ^ (ro&7)) so reads are ~conflict-free.
  auto stage = [&](int pb, int r) {
    long rowstart = (long)(b * R + r) * N + n0;
#pragma unroll
    for (int ci = 0; ci < 4; ci++) {
      int c = w + ci * 8;                 // chunk 0..31 (1 KB each)
      int ro = c >> 1, h = c & 1;
      int sg = h * 64 + lane;             // slot granule (16B units)
      int gg = sg ^ (ro & 7);             // global granule
      const float* gp = adj + (rowstart + ro) * N + gg * 4;
      gload16(gp, (void*)&abuf[pb][ro][h * 256]);
    }
  };

  f32x4 acc = {0.f, 0.f, 0.f, 0.f};
  stage(0, 0);
  __syncthreads();
  for (int r = 0; r < R; r++) {
    int pb = r & 1;
    if (r + 1 < R) stage(pb ^ 1, r + 1);
    const u16* tb = tT + ((long)(b * R + r) * NB + rw) * N;
#pragma unroll
    for (int i = 0; i < 2; i++) {
      int kcol = w * 64 + i * 32 + kq * 8;
      int gr0 = kcol >> 2;                       // even granule
      int sg0 = gr0 ^ (rw & 7);
      int sg1 = (gr0 + 1) ^ (rw & 7);
      float4 a0 = *(const float4*)&abuf[pb][rw][sg0 * 4];
      float4 a1 = *(const float4*)&abuf[pb][rw][sg1 * 4];
      short8 av;
      av[0] = (short)f2u(a0.x); av[1] = (short)f2u(a0.y);
      av[2] = (short)f2u(a0.z); av[3] = (short)f2u(a0.w);
      av[4] = (short)f2u(a1.x); av[5] = (short)f2u(a1.y);
      av[6] = (short)f2u(a1.z); av[7] = (short)f2u(a1.w);
      short8 bv = *(const short8*)(tb + kcol);
      acc = __builtin_amdgcn_mfma_f32_16x16x32_bf16(av, bv, acc, 0, 0, 0);
    }
    __syncthreads();   // drains this wave's stage DMA (vmcnt(0)) + protects buffers
  }

  for (int i = 0; i < 4; i++) hred[w][kq * 4 + i][rw] = acc[i];
  __syncthreads();
  if (tid < 256) {
    int n = tid >> 4, kb = tid & 15;
    float s = 0.f;
    for (int ww = 0; ww < 8; ww++) s += hred[ww][n][kb];
    hbf[n][kb] = f2u(s);
    hbf[n][kb + 16] = 0;
  }
  __syncthreads();

  short8 av = *(const short8*)&hbf[rw][kq * 8];
  short8 bv = *(const short8*)(WwB + (long)(w * 16 + rw) * 32 + kq * 8);
  f32x4 a2 = {0.f, 0.f, 0.f, 0.f};
  a2 = __builtin_amdgcn_mfma_f32_16x16x32_bf16(av, bv, a2, 0, 0, 0);
  int h = w * 16 + rw;
  float wq = wQ[h], wc = wC[h];
  float bsum[4], csum[4];
  for (int i = 0; i < 4; i++) {
    float s = 1.f / (1.f + expf(-(a2[i] + rbv)));
    int n = n0 + kq * 4 + i;
    u16 sv = f2u(s);
    nr[((long)b * N + n) * H + h] = sv;
    nrT[((long)b * H + h) * N + n] = sv;
    bsum[i] = s * wq;
    csum[i] = s * wc;
  }
  for (int i = 0; i < 4; i++) {
    for (int o = 8; o; o >>= 1) { bsum[i] += __shfl_xor(bsum[i], o); csum[i] += __shfl_xor(csum[i], o); }
  }
  if (rw == 0)
    for (int i = 0; i < 4; i++) { bpc[w][kq * 4 + i][0] = bsum[i]; bpc[w][kq * 4 + i][1] = csum[i]; }
  __syncthreads();
  if (tid < 32) {
    int ns = tid & 15, which = tid >> 4;
    float s = 0.f;
    for (int ww = 0; ww < 8; ww++) s += bpc[ww][ns][which];
    (which ? c_n : b_n)[(long)b * N + n0 + ns] = s;
  }
}

// ---------------- k_mm_soft (XCD-swizzled): S-tile in regs; row softmaxes; sq1, sc2, ST.
__global__ __launch_bounds__(512) void k_mm_soft(
    const u16* __restrict__ obsW, const u16* __restrict__ nr,
    const float* __restrict__ b_n, const float* __restrict__ c_n,
    const float* __restrict__ nmask,
    u16* __restrict__ sq1, u16* __restrict__ sc2, u16* __restrict__ ST) {
  int f = blockIdx.x + 16 * blockIdx.y;        // 512 blocks
  int g = (f & 7) * 64 + (f >> 3);
  int mt = g & 15, b = g >> 4;
  int tid = threadIdx.x;
  int w = tid >> 6, lane = tid & 63;
  int rw = lane & 15, kq = lane >> 4;
  __shared__ float sm1[8][16], sm2[8][16], ss1[8][16], ss2[8][16];

  const u16* ap = obsW + ((long)b * Q + mt * 16 + rw) * H + kq * 8;
  const u16* bp = nr + ((long)b * N + w * 64 + rw) * H + kq * 8;
  f32x4 acc[4] = {};
  for (int k = 0; k < H; k += 32) {
    short8 av = *(const short8*)(ap + k);
#pragma unroll
    for (int nt = 0; nt < 4; nt++) {
      short8 bv = *(const short8*)(bp + (long)nt * 16 * H + k);
      acc[nt] = __builtin_amdgcn_mfma_f32_16x16x32_bf16(av, bv, acc[nt], 0, 0, 0);
    }
  }
  float bn[4], cn[4];
  bool mk[4];
  int gcv[4];
#pragma unroll
  for (int nt = 0; nt < 4; nt++) {
    int gc = w * 64 + nt * 16 + rw;
    gcv[nt] = gc;
    mk[nt] = nmask[(long)b * N + gc] > 0.f;
    bn[nt] = b_n[(long)b * N + gc];
    cn[nt] = c_n[(long)b * N + gc];
  }
#pragma unroll
  for (int nt = 0; nt < 4; nt++) {
    long stb = ((long)b * N + gcv[nt]) * Q + mt * 16 + kq * 4;
    for (int i = 0; i < 4; i++) ST[stb + i] = f2u(acc[nt][i]);
  }
  float m1[4], m2[4];
  for (int i = 0; i < 4; i++) { m1[i] = -1e30f; m2[i] = -1e30f; }
#pragma unroll
  for (int nt = 0; nt < 4; nt++)
    for (int i = 0; i < 4; i++) {
      float s = acc[nt][i];
      if (mk[nt]) { m1[i] = fmaxf(m1[i], s + bn[nt]); m2[i] = fmaxf(m2[i], s + cn[nt]); }
    }
  for (int i = 0; i < 4; i++)
    for (int o = 8; o; o >>= 1) { m1[i] = fmaxf(m1[i], __shfl_xor(m1[i], o)); m2[i] = fmaxf(m2[i], __shfl_xor(m2[i], o)); }
  if (rw == 0)
    for (int i = 0; i < 4; i++) { sm1[w][kq * 4 + i] = m1[i]; sm2[w][kq * 4 + i] = m2[i]; }
  __syncthreads();
  for (int i = 0; i < 4; i++) {
    float g1 = -1e30f, g2 = -1e30f;
    for (int ww = 0; ww < 8; ww++) { g1 = fmaxf(g1, sm1[ww][kq * 4 + i]); g2 = fmaxf(g2, sm2[ww][kq * 4 + i]); }
    m1[i] = g1; m2[i] = g2;
  }
  float e1[4][4], e2[4][4];
  float s1[4] = {0.f, 0.f, 0.f, 0.f}, s2[4] = {0.f, 0.f, 0.f, 0.f};
#pragma unroll
  for (int nt = 0; nt < 4; nt++)
    for (int i = 0; i < 4; i++) {
      float s = acc[nt][i];
      float a = mk[nt] ? expf(s + bn[nt] - m1[i]) : 0.f;
      float c = mk[nt] ? expf(s + cn[nt] - m2[i]) : 0.f;
      e1[nt][i] = a; e2[nt][i] = c;
      s1[i] += a; s2[i] += c;
    }
  for (int i = 0; i < 4; i++)
    for (int o = 8; o; o >>= 1) { s1[i] += __shfl_xor(s1[i], o); s2[i] += __shfl_xor(s2[i], o); }
  if (rw == 0)
    for (int i = 0; i < 4; i++) { ss1[w][kq * 4 + i] = s1[i]; ss2[w][kq * 4 + i] = s2[i]; }
  __syncthreads();
  float r1[4], r2[4];
  for (int i = 0; i < 4; i++) {
    float g1 = 0.f, g2 = 0.f;
    for (int ww = 0; ww < 8; ww++) { g1 += ss1[ww][kq * 4 + i]; g2 += ss2[ww][kq * 4 + i]; }
    r1[i] = 1.f / g1; r2[i] = 1.f / g2;
  }
#pragma unroll
  for (int nt = 0; nt < 4; nt++)
    for (int i = 0; i < 4; i++) {
      long ob = ((long)b * Q + mt * 16 + kq * 4 + i) * N + gcv[nt];
      sq1[ob] = f2u(e1[nt][i] * r1[i]);
      sc2[ob] = f2u(e2[nt][i] * r2[i]);
    }
}

// ---------------- col softmax: wave per (b,n) row, 4 waves/block
__global__ __launch_bounds__(256) void k_soft_col(
    const u16* __restrict__ ST, const float* __restrict__ a_o, const float* __restrict__ d_o,
    const float* __restrict__ omask, u16* __restrict__ sc1T, u16* __restrict__ sq2) {
  int w = threadIdx.x >> 6, lane = threadIdx.x & 63;
  long rn = (long)blockIdx.x * 4 + w;   // 16384 rows total
  int b = (int)(rn >> 9);
  float v1[4], v2[4];
  const u16* st = ST + rn * Q + lane * 4;
  for (int i = 0; i < 4; i++) {
    int o = lane * 4 + i;
    float mv = u2f(st[i]);
    bool on = omask[(long)b * Q + o] > 0.f;
    v1[i] = on ? a_o[(long)b * Q + o] + mv : -1e30f;
    v2[i] = on ? d_o[(long)b * Q + o] + mv : -1e30f;
  }
  float m1 = wredmax(fmaxf(fmaxf(v1[0], v1[1]), fmaxf(v1[2], v1[3])));
  float m2 = wredmax(fmaxf(fmaxf(v2[0], v2[1]), fmaxf(v2[2], v2[3])));
  float e1[4], e2[4], s1 = 0.f, s2 = 0.f;
  for (int i = 0; i < 4; i++) {
    e1[i] = expf(v1[i] - m1); e2[i] = expf(v2[i] - m2);
    s1 += e1[i]; s2 += e2[i];
  }
  s1 = wredsum(s1); s2 = wredsum(s2);
  float r1 = 1.f / s1, r2 = 1.f / s2;
  for (int i = 0; i < 4; i++) {
    sc1T[rn * Q + lane * 4 + i] = f2u(e1[i] * r1);
    sq2[rn * Q + lane * 4 + i] = f2u(e2[i] * r2);
  }
}

// ---------------- 16x128 GEMM tile worker ----------------
DEVI void gemm_tile(const u16* A, const u16* Bt, u16* C, int Mdim, int Kdim,
                    long sA, long sBt, long sC, int tc, int batch, int mt, int lane) {
  if (mt * 16 >= Mdim) return;
  int rw = lane & 15, kq = lane >> 4;
  const u16* ap = A + (long)batch * sA + (long)(mt * 16 + rw) * Kdim + kq * 8;
  const u16* bp = Bt + (long)batch * sBt + (long)rw * Kdim + kq * 8;
  f32x4 acc[8] = {};
  for (int k = 0; k < Kdim; k += 32) {
    short8 av = *(const short8*)(ap + k);
#pragma unroll
    for (int nt = 0; nt < 8; nt++) {
      short8 bv = *(const short8*)(bp + (long)nt * 16 * Kdim + k);
      acc[nt] = __builtin_amdgcn_mfma_f32_16x16x32_bf16(av, bv, acc[nt], 0, 0, 0);
    }
  }
#pragma unroll
  for (int nt = 0; nt < 8; nt++) {
    int gc = nt * 16 + rw;
    for (int i = 0; i < 4; i++) {
      int gr = mt * 16 + kq * 4 + i;
      long idx = tc ? ((long)gc * Mdim + gr) : ((long)gr * H + gc);
      C[(long)batch * sC + idx] = f2u(acc[nt][i]);
    }
  }
}

// ---------------- phase A: P1 | T2T | T1T | P2 (4096 tiles, XCD-swizzled 1D)
__global__ __launch_bounds__(64) void k_gemmA(
    const u16* __restrict__ sq1, const u16* __restrict__ sc2,
    const u16* __restrict__ sc1T, const u16* __restrict__ sq2,
    const u16* __restrict__ nrT, const u16* __restrict__ obsT,
    u16* __restrict__ P1, u16* __restrict__ T2T, u16* __restrict__ T1T, u16* __restrict__ P2) {
  int bid = blockIdx.x;
  int t = (bid & 7) * 512 + (bid >> 3);
  int z = t >> 10, rem = t & 1023, batch = rem >> 5, mt = rem & 31;
  int lane = threadIdx.x;
  if (z == 0)      gemm_tile(sq1,  nrT,  P1,  Q, N, (long)Q * N, (long)H * N, (long)Q * H, 0, batch, mt, lane);
  else if (z == 1) gemm_tile(sc2,  nrT,  T2T, Q, N, (long)Q * N, (long)H * N, (long)H * Q, 1, batch, mt, lane);
  else if (z == 2) gemm_tile(sc1T, obsT, T1T, N, Q, (long)N * Q, (long)H * Q, (long)H * N, 1, batch, mt, lane);
  else             gemm_tile(sq2,  obsT, P2,  N, Q, (long)N * Q, (long)H * Q, (long)N * H, 0, batch, mt, lane);
}

// ---------------- phase B: Qm1 | Qm2 (2048 tiles, XCD-swizzled 1D)
__global__ __launch_bounds__(64) void k_gemmB(
    const u16* __restrict__ sq1, const u16* __restrict__ sq2,
    const u16* __restrict__ T1T, const u16* __restrict__ T2T,
    u16* __restrict__ Qm1, u16* __restrict__ Qm2) {
  int bid = blockIdx.x;
  int t = (bid & 7) * 256 + (bid >> 3);
  int z = t >> 10, rem = t & 1023, batch = rem >> 5, mt = rem & 31;
  int lane = threadIdx.x;
  if (z == 0) gemm_tile(sq1, T1T, Qm1, Q, N, (long)Q * N, (long)H * N, (long)Q * H, 0, batch, mt, lane);
  else        gemm_tile(sq2, T2T, Qm2, N, Q, (long)N * Q, (long)H * Q, (long)N * H, 0, batch, mt, lane);
}

// ---------------- phase C: concat + output linear (2048 tiles, XCD-swizzled 1D)
__global__ __launch_bounds__(64) void k_cat(
    const float* __restrict__ obs, const u16* __restrict__ nrr,
    const u16* __restrict__ P1, const u16* __restrict__ Qm1,
    const u16* __restrict__ P2, const u16* __restrict__ Qm2,
    const u16* __restrict__ Wt, const float* __restrict__ bias,
    float* __restrict__ out0, float* __restrict__ out1) {
  int bid = blockIdx.x;
  int t = (bid & 7) * 256 + (bid >> 3);
  int z = t >> 10, rem = t & 1023, batch = rem >> 5, mt = rem & 31;
  int Mdim = z ? N : Q;
  if (mt * 16 >= Mdim) return;
  const u16* P = z ? P2 : P1;
  const u16* Qm = z ? Qm2 : Qm1;
  float* out = z ? out1 : out0;
  int lane = threadIdx.x;
  int rw = lane & 15, kq = lane >> 4;
  long arow = (long)batch * Mdim + mt * 16 + rw;
  const u16* bp = Wt + (long)rw * (4 * H) + kq * 8;
  f32x4 acc[8] = {};
  for (int k = 0; k < 4 * H; k += 32) {
    int sec = k >> 7;
    int off = (k & 127) + kq * 8;
    long rb2 = arow * H + off;
    short8 av;
    if (sec == 0) {
      if (!z) av = cvt8(obs + rb2);
      else    av = *(const short8*)(nrr + rb2);
    } else if (sec == 1) {
      av = *(const short8*)(P + rb2);
    } else {
      float xf[8];
      if (!z) {
        const float* xp = obs + rb2;
        float4 f0 = *(const float4*)xp;
        float4 f1 = *(const float4*)(xp + 4);
        xf[0] = f0.x; xf[1] = f0.y; xf[2] = f0.z; xf[3] = f0.w;
        xf[4] = f1.x; xf[5] = f1.y; xf[6] = f1.z; xf[7] = f1.w;
      } else {
        short8 xv = *(const short8*)(nrr + rb2);
        for (int i = 0; i < 8; i++) xf[i] = u2f((u16)xv[i]);
      }
      short8 pv = *(const short8*)((sec == 2 ? P : Qm) + rb2);
      for (int i = 0; i < 8; i++) av[i] = (short)f2u(xf[i] * u2f((u16)pv[i]));
    }
#pragma unroll
    for (int nt = 0; nt < 8; nt++) {
      short8 bv = *(const short8*)(bp + (long)nt * 16 * (4 * H) + k);
      acc[nt] = __builtin_amdgcn_mfma_f32_16x16x32_bf16(av, bv, acc[nt], 0, 0, 0);
    }
  }
#pragma unroll
  for (int nt = 0; nt < 8; nt++) {
    int gc = nt * 16 + rw;
    float cb = bias[gc];
    for (int i = 0; i < 4; i++) {
      int gr = mt * 16 + kq * 4 + i;
      out[((long)batch * Mdim + gr) * H + gc] = acc[nt][i] + cb;
    }
  }
}

// ---------------- launch ----------------
extern "C" void kernel_launch(void* const* d_in, const int* in_sizes, int n_in,
                              void* d_out, int out_size, void* d_ws, size_t ws_size,
                              hipStream_t stream) {
  const float* nf    = (const float*)d_in[0];
  const float* rf    = (const float*)d_in[1];
  const float* adj   = (const float*)d_in[2];
  const float* obs   = (const float*)d_in[3];
  const float* nmask = (const float*)d_in[4];
  const float* omask = (const float*)d_in[5];
  const float* Wb    = (const float*)d_in[6];
  const float* Ww    = (const float*)d_in[7];
  const float* rb    = (const float*)d_in[8];
  const float* wC    = (const float*)d_in[9];
  const float* wQ    = (const float*)d_in[10];
  const float* wCQ   = (const float*)d_in[11];
  // d_in[12] = cq_bias: uniform shift along both softmax axes -> cancels, unused
  const float* linW  = (const float*)d_in[13];
  const float* linb  = (const float*)d_in[14];
  float* outp = (float*)d_out;

  char* w = (char*)d_ws;
  auto alloc = [&](size_t bytes) { char* p = w; w += (bytes + 255) & ~(size_t)255; return p; };
  u16*   linWb = (u16*)  alloc((size_t)H * 4 * H * 2);
  u16*   WbB   = (u16*)  alloc((size_t)R * NB * 128 * 2);
  u16*   WwB   = (u16*)  alloc((size_t)H * 32 * 2);
  float* vv    = (float*)alloc((size_t)B * R * NB * 4);
  u16*   obsW  = (u16*)  alloc((size_t)B * Q * H * 2);
  u16*   obsT  = (u16*)  alloc((size_t)B * H * Q * 2);
  float* a_o   = (float*)alloc((size_t)B * Q * 4);
  float* d_o   = (float*)alloc((size_t)B * Q * 4);
  float* b_n   = (float*)alloc((size_t)B * N * 4);
  float* c_n   = (float*)alloc((size_t)B * N * 4);
  u16*   nr    = (u16*)  alloc((size_t)B * N * H * 2);
  u16*   nrT   = (u16*)  alloc((size_t)B * H * N * 2);
  u16*   tT    = (u16*)  alloc((size_t)B * R * NB * N * 2);
  u16*   ST    = (u16*)  alloc((size_t)B * N * Q * 2);
  u16*   sq1   = (u16*)  alloc((size_t)B * Q * N * 2);
  u16*   sc2   = (u16*)  alloc((size_t)B * Q * N * 2);
  u16*   sc1T  = (u16*)  alloc((size_t)B * N * Q * 2);
  u16*   sq2   = (u16*)  alloc((size_t)B * N * Q * 2);
  u16*   P1    = (u16*)  alloc((size_t)B * Q * H * 2);
  u16*   T1T   = (u16*)  alloc((size_t)B * H * N * 2);
  u16*   Qm1   = (u16*)  alloc((size_t)B * Q * H * 2);
  u16*   P2    = (u16*)  alloc((size_t)B * N * H * 2);
  u16*   T2T   = (u16*)  alloc((size_t)B * H * Q * 2);
  u16*   Qm2   = (u16*)  alloc((size_t)B * N * H * 2);
  float* out1  = outp + (long)B * Q * H;

  // 1. prep
  k_prep<<<6560, 256, 0, stream>>>(linW, linWb, Wb, WbB, Ww, WwB,
                                   rf, vv, obs, wC, wQ, wCQ, obsW, a_o, d_o, obsT);
  // 2. tT
  k_tt<<<dim3(N / 128, B), 512, 0, stream>>>(WbB, nf, vv, tT);
  // 3. mega RGCN (double-buffered global_load_lds adj pipeline)
  k_rgcn<<<dim3(N / 16, B), 512, 0, stream>>>(adj, tT, WwB, rb, wC, wQ, nr, nrT, b_n, c_n);
  // 4. S + row softmaxes
  k_mm_soft<<<dim3(Q / 16, B), 512, 0, stream>>>(obsW, nr, b_n, c_n, nmask, sq1, sc2, ST);
  // 5. col softmax (wave per row)
  k_soft_col<<<B * N / 4, 256, 0, stream>>>(ST, a_o, d_o, omask, sc1T, sq2);
  // 6. phase A GEMMs
  k_gemmA<<<4096, 64, 0, stream>>>(sq1, sc2, sc1T, sq2, nrT, obsT, P1, T2T, T1T, P2);
  // 7. phase B GEMMs
  k_gemmB<<<2048, 64, 0, stream>>>(sq1, sq2, T1T, T2T, Qm1, Qm2);
  // 8. concat + output linear
  k_cat<<<2048, 64, 0, stream>>>(obs, nr, P1, Qm1, P2, Qm2, linWb, linb, outp, out1);

  (void)in_sizes; (void)n_in; (void)out_size; (void)ws_size;
}